// Round 19
// baseline (137.594 us; speedup 1.0000x reference)
//
#include <hip/hip_runtime.h>
#include <math.h>

using short8v = __attribute__((ext_vector_type(8))) short;
using f32x4   = __attribute__((ext_vector_type(4))) float;

constexpr int BCAP = 8192;  // per-bucket capacity (mean ~4081, >60 sigma headroom)

// ---------------- bf16 helpers ----------------

__device__ inline float bf_lo(unsigned int p) { return __uint_as_float(p << 16); }
__device__ inline float bf_hi(unsigned int p) { return __uint_as_float(p & 0xffff0000u); }
__device__ inline unsigned short f2bf(float f) {  // round-to-nearest-even
    unsigned int u = __float_as_uint(f);
    u += 0x7fffu + ((u >> 16) & 1u);
    return (unsigned short)(u >> 16);
}
__device__ inline unsigned int pack2bf(float a, float b) {
    return (unsigned int)f2bf(a) | ((unsigned int)f2bf(b) << 16);
}

// ------- prep: init bucket cursors + W1/W2 -> frag-major bf16 in global -------
// frag layout (per MFMA 16x16x32 B-operand): elem index e = ((c*KK+kk)*64 + l)*8 + j
// maps to W[kk*32 + (l>>4)*8 + j][c*16 + (l&15)].

__global__ __launch_bounds__(256)
void prep_kernel(const float* __restrict__ W1, const float* __restrict__ W2,
                 unsigned short* __restrict__ w1f, unsigned short* __restrict__ w2f,
                 int* __restrict__ bcur, int nb) {
    int i = blockIdx.x * 256 + threadIdx.x;
    if (i < nb) bcur[i] = i * BCAP;
    if (i < 8 * 2 * 64 * 8) {  // 8192 = K64 frags (KK=2)
        int j = i & 7, l = (i >> 3) & 63, rest = i >> 9;
        int kk = rest & 1, c = rest >> 1;
        int rk = kk * 32 + (l >> 4) * 8 + j;
        int cc = c * 16 + (l & 15);
        w1f[i] = f2bf(W1[rk * 128 + cc]);
    }
    if (i < 8 * 4 * 64 * 8) {  // 16384 = K128 frags (KK=4)
        int j = i & 7, l = (i >> 3) & 63, rest = i >> 9;
        int kk = rest & 3, c = rest >> 2;
        int rk = kk * 32 + (l >> 4) * 8 + j;
        int cc = c * 16 + (l & 15);
        w2f[i] = f2bf(W2[rk * 128 + cc]);
    }
}

// ---------------- partition: bucket edges by dst>>8; 4096 edges/block ----------------
// packed entry: (src << 8) | (dst & 255)   [valid: N < 65536]

__global__ __launch_bounds__(1024)
void partA_kernel(const int* __restrict__ src, const int* __restrict__ dst,
                  int* __restrict__ bcur, unsigned int* __restrict__ tmp, int E) {
    __shared__ int hist[256];
    __shared__ int chunk[256];
    int t = threadIdx.x;
    if (t < 256) hist[t] = 0;
    __syncthreads();
    int base = blockIdx.x * 4096;
    int s[4], d[4], bb[4], lr[4];
    bool val[4];
#pragma unroll
    for (int k = 0; k < 4; ++k) {
        int i = base + k * 1024 + t;
        val[k] = i < E;
        if (val[k]) {
            s[k] = src[i];
            d[k] = dst[i];
            bb[k] = d[k] >> 8;
            lr[k] = atomicAdd(&hist[bb[k]], 1);  // LDS: local rank in (block,bucket)
        }
    }
    __syncthreads();
    if (t < 256) {
        int c = hist[t];
        chunk[t] = (c > 0) ? atomicAdd(&bcur[t], c) : 0;
    }
    __syncthreads();
#pragma unroll
    for (int k = 0; k < 4; ++k) {
        if (val[k]) tmp[chunk[bb[k]] + lr[k]] = ((unsigned int)s[k] << 8) | (unsigned int)(d[k] & 255);
    }
}

// ------- bucket_build: folded bucket-scan + per-bucket CSR + dinv + prescaled z -------

__global__ __launch_bounds__(256)
void bucket_build_kernel(const unsigned int* __restrict__ tmp, const int* __restrict__ bcur,
                         const float* __restrict__ z, int* __restrict__ rowptr,
                         float* __restrict__ dinv, int* __restrict__ col,
                         unsigned int* __restrict__ zsb, int N, int nb, int E) {
    __shared__ int s[256];
    __shared__ int h[256];
    __shared__ int sc[256];
    __shared__ int cur[256];
    __shared__ float sdv[256];
    __shared__ int s_eb;
    int b = blockIdx.x;
    int t = threadIdx.x;
    // folded bscan: every block scans all bucket counts (196 ints, trivial)
    int cnt_t = (t < nb) ? (bcur[t] - t * BCAP) : 0;
    s[t] = cnt_t;
    __syncthreads();
    for (int off = 1; off < 256; off <<= 1) {
        int u = (t >= off) ? s[t - off] : 0;
        __syncthreads();
        s[t] += u;
        __syncthreads();
    }
    if (t == b) s_eb = s[t] - cnt_t;  // exclusive prefix for this bucket
    if (b == 0 && t == 0) rowptr[N] = E;
    h[t] = 0;
    __syncthreads();
    int eb = s_eb;
    int base = b * BCAP;
    int ecnt = bcur[b] - base;
    // per-node histogram
    for (int i = t; i < ecnt; i += 256) {
        atomicAdd(&h[tmp[base + i] & 255], 1);
    }
    __syncthreads();
    int v = h[t];
    sc[t] = v;
    __syncthreads();
    for (int off = 1; off < 256; off <<= 1) {
        int u = (t >= off) ? sc[t - off] : 0;
        __syncthreads();
        sc[t] += u;
        __syncthreads();
    }
    int excl = sc[t] - v;
    int nd = b * 256 + t;
    float dv = rsqrtf((float)v + 1.0f);  // degree incl. self-loop
    if (nd < N) {
        rowptr[nd] = eb + excl;
        dinv[nd] = dv;
    }
    sdv[t] = dv;
    cur[t] = excl;
    __syncthreads();
    // scatter col (LDS cursors, contiguous window)
    for (int i = t; i < ecnt; i += 256) {
        unsigned int e = tmp[base + i];
        int lpos = atomicAdd(&cur[e & 255], 1);
        col[eb + lpos] = (int)(e >> 8);
    }
    // prescale this block's 256 z-rows: zs = bf16(dinv * z), packed pairs (32 uints/row)
    int nd0 = b * 256;
    for (int idx = t; idx < 256 * 32; idx += 256) {
        int row = idx >> 5;
        int p = idx & 31;
        int node = nd0 + row;
        if (node < N) {
            float2 zv = ((const float2*)z)[(size_t)node * 32 + p];
            float d = sdv[row];
            zsb[(size_t)node * 32 + p] = pack2bf(d * zv.x, d * zv.y);
        }
    }
}

// ------- fused1: [agg64 over zs] -> LDS A-tile -> MFMA W1 -> hs = bf16(dinv.*relu(.+b1)) -------
// 1 tile/block. Phase A: quarter-wave per row (16 lanes x uint2 = 128 B row), DUAL EDGE STREAMS
// per row ([beg,mid) and [mid,end), lenA>=lenB) x 8-edge unroll = 16 gathers in flight/quarter.
// Phase B: 16x32 col slice per wave.
// mfma_f32_16x16x32_bf16 frags: A lane l: row=l&15, k=(l>>4)*8+j ; B: col=l&15, k=(l>>4)*8+j ;
// C/D: col=l&15, row=(l>>4)*4+j  [m89-verified].

__global__ __launch_bounds__(256)
void fused1_kernel(const uint2* __restrict__ zs4, const int* __restrict__ rowptr,
                   const int* __restrict__ col, const float* __restrict__ dinv,
                   const unsigned short* __restrict__ w1f, const float* __restrict__ b1,
                   unsigned short* __restrict__ hsb, int n) {
    __shared__ unsigned int Atile[16][36];  // row-stride 36 uints (16B pad -> 2-way banks)
    int t = threadIdx.x;
    int wv = t >> 6, lane = t & 63;
    int tile = blockIdx.x;
    int quarter = lane >> 4, ql = lane & 15;  // lane ql holds feats 4ql..4ql+3

    // Phase A: one row per quarter-wave, dual edge streams
    {
        int r = wv * 4 + quarter;
        int row = tile * 16 + r;
        float a0 = 0.0f, a1 = 0.0f, a2 = 0.0f, a3 = 0.0f;
        float g0 = 0.0f, g1 = 0.0f, g2 = 0.0f, g3 = 0.0f;
        if (row < n) {
            int beg = rowptr[row];
            int end = rowptr[row + 1];
            float di = dinv[row];
            int mid = beg + ((end - beg + 1) >> 1);  // lenA >= lenB
            uint2 sp = zs4[(size_t)row * 16 + ql];
            a0 = bf_lo(sp.x); a1 = bf_hi(sp.x);
            a2 = bf_lo(sp.y); a3 = bf_hi(sp.y);
            int e1 = beg, e2 = mid;
            for (; e2 + 7 < end; e1 += 8, e2 += 8) {
                int cA0 = col[e1], cA1 = col[e1 + 1], cA2 = col[e1 + 2], cA3 = col[e1 + 3];
                int cA4 = col[e1 + 4], cA5 = col[e1 + 5], cA6 = col[e1 + 6], cA7 = col[e1 + 7];
                int cB0 = col[e2], cB1 = col[e2 + 1], cB2 = col[e2 + 2], cB3 = col[e2 + 3];
                int cB4 = col[e2 + 4], cB5 = col[e2 + 5], cB6 = col[e2 + 6], cB7 = col[e2 + 7];
                uint2 pA0 = zs4[(size_t)cA0 * 16 + ql];
                uint2 pA1 = zs4[(size_t)cA1 * 16 + ql];
                uint2 pA2 = zs4[(size_t)cA2 * 16 + ql];
                uint2 pA3 = zs4[(size_t)cA3 * 16 + ql];
                uint2 pA4 = zs4[(size_t)cA4 * 16 + ql];
                uint2 pA5 = zs4[(size_t)cA5 * 16 + ql];
                uint2 pA6 = zs4[(size_t)cA6 * 16 + ql];
                uint2 pA7 = zs4[(size_t)cA7 * 16 + ql];
                uint2 pB0 = zs4[(size_t)cB0 * 16 + ql];
                uint2 pB1 = zs4[(size_t)cB1 * 16 + ql];
                uint2 pB2 = zs4[(size_t)cB2 * 16 + ql];
                uint2 pB3 = zs4[(size_t)cB3 * 16 + ql];
                uint2 pB4 = zs4[(size_t)cB4 * 16 + ql];
                uint2 pB5 = zs4[(size_t)cB5 * 16 + ql];
                uint2 pB6 = zs4[(size_t)cB6 * 16 + ql];
                uint2 pB7 = zs4[(size_t)cB7 * 16 + ql];
                a0 += bf_lo(pA0.x); a1 += bf_hi(pA0.x); a2 += bf_lo(pA0.y); a3 += bf_hi(pA0.y);
                a0 += bf_lo(pA1.x); a1 += bf_hi(pA1.x); a2 += bf_lo(pA1.y); a3 += bf_hi(pA1.y);
                a0 += bf_lo(pA2.x); a1 += bf_hi(pA2.x); a2 += bf_lo(pA2.y); a3 += bf_hi(pA2.y);
                a0 += bf_lo(pA3.x); a1 += bf_hi(pA3.x); a2 += bf_lo(pA3.y); a3 += bf_hi(pA3.y);
                a0 += bf_lo(pA4.x); a1 += bf_hi(pA4.x); a2 += bf_lo(pA4.y); a3 += bf_hi(pA4.y);
                a0 += bf_lo(pA5.x); a1 += bf_hi(pA5.x); a2 += bf_lo(pA5.y); a3 += bf_hi(pA5.y);
                a0 += bf_lo(pA6.x); a1 += bf_hi(pA6.x); a2 += bf_lo(pA6.y); a3 += bf_hi(pA6.y);
                a0 += bf_lo(pA7.x); a1 += bf_hi(pA7.x); a2 += bf_lo(pA7.y); a3 += bf_hi(pA7.y);
                g0 += bf_lo(pB0.x); g1 += bf_hi(pB0.x); g2 += bf_lo(pB0.y); g3 += bf_hi(pB0.y);
                g0 += bf_lo(pB1.x); g1 += bf_hi(pB1.x); g2 += bf_lo(pB1.y); g3 += bf_hi(pB1.y);
                g0 += bf_lo(pB2.x); g1 += bf_hi(pB2.x); g2 += bf_lo(pB2.y); g3 += bf_hi(pB2.y);
                g0 += bf_lo(pB3.x); g1 += bf_hi(pB3.x); g2 += bf_lo(pB3.y); g3 += bf_hi(pB3.y);
                g0 += bf_lo(pB4.x); g1 += bf_hi(pB4.x); g2 += bf_lo(pB4.y); g3 += bf_hi(pB4.y);
                g0 += bf_lo(pB5.x); g1 += bf_hi(pB5.x); g2 += bf_lo(pB5.y); g3 += bf_hi(pB5.y);
                g0 += bf_lo(pB6.x); g1 += bf_hi(pB6.x); g2 += bf_lo(pB6.y); g3 += bf_hi(pB6.y);
                g0 += bf_lo(pB7.x); g1 += bf_hi(pB7.x); g2 += bf_lo(pB7.y); g3 += bf_hi(pB7.y);
            }
            for (; e1 < mid; ++e1) {
                uint2 p = zs4[(size_t)col[e1] * 16 + ql];
                a0 += bf_lo(p.x); a1 += bf_hi(p.x);
                a2 += bf_lo(p.y); a3 += bf_hi(p.y);
            }
            for (; e2 < end; ++e2) {
                uint2 p = zs4[(size_t)col[e2] * 16 + ql];
                g0 += bf_lo(p.x); g1 += bf_hi(p.x);
                g2 += bf_lo(p.y); g3 += bf_hi(p.y);
            }
            a0 = (a0 + g0) * di; a1 = (a1 + g1) * di;
            a2 = (a2 + g2) * di; a3 = (a3 + g3) * di;
        }
        Atile[r][2 * ql]     = pack2bf(a0, a1);
        Atile[r][2 * ql + 1] = pack2bf(a2, a3);
    }
    __syncthreads();

    // Phase B: wave wv computes cols [wv*32, wv*32+32) = c-frags {wv*2, wv*2+1}
    const short8v* bfr = (const short8v*)w1f;
    const unsigned int* ap = &Atile[0][0];
    short8v af[2];
#pragma unroll
    for (int kk = 0; kk < 2; ++kk) {
        af[kk] = *(const short8v*)(ap + (lane & 15) * 36 + kk * 16 + (lane >> 4) * 4);
    }
    f32x4 acc[2];
#pragma unroll
    for (int ci = 0; ci < 2; ++ci) acc[ci] = (f32x4){0.0f, 0.0f, 0.0f, 0.0f};
#pragma unroll
    for (int kk = 0; kk < 2; ++kk) {
#pragma unroll
        for (int ci = 0; ci < 2; ++ci) {
            int c = wv * 2 + ci;
            acc[ci] = __builtin_amdgcn_mfma_f32_16x16x32_bf16(af[kk], bfr[(c * 2 + kk) * 64 + lane],
                                                              acc[ci], 0, 0, 0);
        }
    }
    int colbase = lane & 15;
    int rowg = (lane >> 4) * 4;
    float dvj[4];
#pragma unroll
    for (int j = 0; j < 4; ++j) {
        int row = tile * 16 + rowg + j;
        dvj[j] = (row < n) ? dinv[row] : 1.0f;
    }
#pragma unroll
    for (int ci = 0; ci < 2; ++ci) {
        int c = wv * 2 + ci;
        float bv = b1[c * 16 + colbase];
#pragma unroll
        for (int j = 0; j < 4; ++j) {
            int row = tile * 16 + rowg + j;
            if (row < n) {
                float v = fmaxf(acc[ci][j] + bv, 0.0f) * dvj[j];
                hsb[(size_t)row * 128 + c * 16 + colbase] = f2bf(v);
            }
        }
    }
}

// ------- fused2: [agg128 over hs] -> LDS A-tile -> MFMA W2 -> out fp32 (+b2) -------
// Phase A: quarter-wave per row (16 lanes x uint4 = 256 B row), DUAL EDGE STREAMS x 4-edge
// unroll = 8 uint4 gathers in flight/quarter. Lane ql holds feats 8ql..8ql+7.

__global__ __launch_bounds__(256)
void fused2_kernel(const uint4* __restrict__ hs8, const int* __restrict__ rowptr,
                   const int* __restrict__ col, const float* __restrict__ dinv,
                   const unsigned short* __restrict__ w2f, const float* __restrict__ b2,
                   float* __restrict__ out, int n) {
    __shared__ unsigned int Atile[16][68];  // row-stride 68 uints (16B pad)
    int t = threadIdx.x;
    int wv = t >> 6, lane = t & 63;
    int tile = blockIdx.x;
    int quarter = lane >> 4, ql = lane & 15;

    // Phase A: one row per quarter-wave, dual edge streams
    {
        int r = wv * 4 + quarter;
        int row = tile * 16 + r;
        float a0 = 0.0f, a1 = 0.0f, a2 = 0.0f, a3 = 0.0f;
        float a4 = 0.0f, a5 = 0.0f, a6 = 0.0f, a7 = 0.0f;
        float g0 = 0.0f, g1 = 0.0f, g2 = 0.0f, g3 = 0.0f;
        float g4 = 0.0f, g5 = 0.0f, g6 = 0.0f, g7 = 0.0f;
        if (row < n) {
            int beg = rowptr[row];
            int end = rowptr[row + 1];
            float di = dinv[row];
            int mid = beg + ((end - beg + 1) >> 1);  // lenA >= lenB
            uint4 sp = hs8[(size_t)row * 16 + ql];
            a0 = bf_lo(sp.x); a1 = bf_hi(sp.x);
            a2 = bf_lo(sp.y); a3 = bf_hi(sp.y);
            a4 = bf_lo(sp.z); a5 = bf_hi(sp.z);
            a6 = bf_lo(sp.w); a7 = bf_hi(sp.w);
            int e1 = beg, e2 = mid;
            for (; e2 + 3 < end; e1 += 4, e2 += 4) {
                int cA0 = col[e1], cA1 = col[e1 + 1], cA2 = col[e1 + 2], cA3 = col[e1 + 3];
                int cB0 = col[e2], cB1 = col[e2 + 1], cB2 = col[e2 + 2], cB3 = col[e2 + 3];
                uint4 pA0 = hs8[(size_t)cA0 * 16 + ql];
                uint4 pA1 = hs8[(size_t)cA1 * 16 + ql];
                uint4 pA2 = hs8[(size_t)cA2 * 16 + ql];
                uint4 pA3 = hs8[(size_t)cA3 * 16 + ql];
                uint4 pB0 = hs8[(size_t)cB0 * 16 + ql];
                uint4 pB1 = hs8[(size_t)cB1 * 16 + ql];
                uint4 pB2 = hs8[(size_t)cB2 * 16 + ql];
                uint4 pB3 = hs8[(size_t)cB3 * 16 + ql];
                a0 += bf_lo(pA0.x); a1 += bf_hi(pA0.x); a2 += bf_lo(pA0.y); a3 += bf_hi(pA0.y);
                a4 += bf_lo(pA0.z); a5 += bf_hi(pA0.z); a6 += bf_lo(pA0.w); a7 += bf_hi(pA0.w);
                a0 += bf_lo(pA1.x); a1 += bf_hi(pA1.x); a2 += bf_lo(pA1.y); a3 += bf_hi(pA1.y);
                a4 += bf_lo(pA1.z); a5 += bf_hi(pA1.z); a6 += bf_lo(pA1.w); a7 += bf_hi(pA1.w);
                a0 += bf_lo(pA2.x); a1 += bf_hi(pA2.x); a2 += bf_lo(pA2.y); a3 += bf_hi(pA2.y);
                a4 += bf_lo(pA2.z); a5 += bf_hi(pA2.z); a6 += bf_lo(pA2.w); a7 += bf_hi(pA2.w);
                a0 += bf_lo(pA3.x); a1 += bf_hi(pA3.x); a2 += bf_lo(pA3.y); a3 += bf_hi(pA3.y);
                a4 += bf_lo(pA3.z); a5 += bf_hi(pA3.z); a6 += bf_lo(pA3.w); a7 += bf_hi(pA3.w);
                g0 += bf_lo(pB0.x); g1 += bf_hi(pB0.x); g2 += bf_lo(pB0.y); g3 += bf_hi(pB0.y);
                g4 += bf_lo(pB0.z); g5 += bf_hi(pB0.z); g6 += bf_lo(pB0.w); g7 += bf_hi(pB0.w);
                g0 += bf_lo(pB1.x); g1 += bf_hi(pB1.x); g2 += bf_lo(pB1.y); g3 += bf_hi(pB1.y);
                g4 += bf_lo(pB1.z); g5 += bf_hi(pB1.z); g6 += bf_lo(pB1.w); g7 += bf_hi(pB1.w);
                g0 += bf_lo(pB2.x); g1 += bf_hi(pB2.x); g2 += bf_lo(pB2.y); g3 += bf_hi(pB2.y);
                g4 += bf_lo(pB2.z); g5 += bf_hi(pB2.z); g6 += bf_lo(pB2.w); g7 += bf_hi(pB2.w);
                g0 += bf_lo(pB3.x); g1 += bf_hi(pB3.x); g2 += bf_lo(pB3.y); g3 += bf_hi(pB3.y);
                g4 += bf_lo(pB3.z); g5 += bf_hi(pB3.z); g6 += bf_lo(pB3.w); g7 += bf_hi(pB3.w);
            }
            for (; e1 < mid; ++e1) {
                uint4 p = hs8[(size_t)col[e1] * 16 + ql];
                a0 += bf_lo(p.x); a1 += bf_hi(p.x); a2 += bf_lo(p.y); a3 += bf_hi(p.y);
                a4 += bf_lo(p.z); a5 += bf_hi(p.z); a6 += bf_lo(p.w); a7 += bf_hi(p.w);
            }
            for (; e2 < end; ++e2) {
                uint4 p = hs8[(size_t)col[e2] * 16 + ql];
                g0 += bf_lo(p.x); g1 += bf_hi(p.x); g2 += bf_lo(p.y); g3 += bf_hi(p.y);
                g4 += bf_lo(p.z); g5 += bf_hi(p.z); g6 += bf_lo(p.w); g7 += bf_hi(p.w);
            }
            a0 = (a0 + g0) * di; a1 = (a1 + g1) * di;
            a2 = (a2 + g2) * di; a3 = (a3 + g3) * di;
            a4 = (a4 + g4) * di; a5 = (a5 + g5) * di;
            a6 = (a6 + g6) * di; a7 = (a7 + g7) * di;
        }
        Atile[r][4 * ql]     = pack2bf(a0, a1);
        Atile[r][4 * ql + 1] = pack2bf(a2, a3);
        Atile[r][4 * ql + 2] = pack2bf(a4, a5);
        Atile[r][4 * ql + 3] = pack2bf(a6, a7);
    }
    __syncthreads();

    // Phase B: wave wv computes cols [wv*32, wv*32+32) = c-frags {wv*2, wv*2+1}
    const short8v* bfr = (const short8v*)w2f;
    const unsigned int* ap = &Atile[0][0];
    short8v af[4];
#pragma unroll
    for (int kk = 0; kk < 4; ++kk) {
        af[kk] = *(const short8v*)(ap + (lane & 15) * 68 + kk * 16 + (lane >> 4) * 4);
    }
    f32x4 acc[2];
#pragma unroll
    for (int ci = 0; ci < 2; ++ci) acc[ci] = (f32x4){0.0f, 0.0f, 0.0f, 0.0f};
#pragma unroll
    for (int kk = 0; kk < 4; ++kk) {
#pragma unroll
        for (int ci = 0; ci < 2; ++ci) {
            int c = wv * 2 + ci;
            acc[ci] = __builtin_amdgcn_mfma_f32_16x16x32_bf16(af[kk], bfr[(c * 4 + kk) * 64 + lane],
                                                              acc[ci], 0, 0, 0);
        }
    }
    int colbase = lane & 15;
    int rowg = (lane >> 4) * 4;
#pragma unroll
    for (int ci = 0; ci < 2; ++ci) {
        int c = wv * 2 + ci;
        float bv = b2[c * 16 + colbase];
#pragma unroll
        for (int j = 0; j < 4; ++j) {
            int row = tile * 16 + rowg + j;
            if (row < n) {
                out[(size_t)row * 128 + c * 16 + colbase] = acc[ci][j] + bv;
            }
        }
    }
}

// ---------------- launch ----------------

extern "C" void kernel_launch(void* const* d_in, const int* in_sizes, int n_in,
                              void* d_out, int out_size, void* d_ws, size_t ws_size,
                              hipStream_t stream) {
    const float* z  = (const float*)d_in[0];
    const int*   ei = (const int*)d_in[1];
    const float* W1 = (const float*)d_in[2];
    const float* b1 = (const float*)d_in[3];
    const float* W2 = (const float*)d_in[4];
    const float* b2 = (const float*)d_in[5];
    float* out = (float*)d_out;

    int N = in_sizes[0] / 64;
    int E = in_sizes[1] / 2;
    const int* srcp = ei;
    const int* dstp = ei + E;

    char* w = (char*)d_ws;
    auto alloc = [&](size_t bytes) -> char* {
        char* p = w;
        w += (bytes + 255) & ~(size_t)255;
        return p;
    };
    int nb = (N + 255) / 256;  // 196 for N=50000 (must be <= 256)

    int*   rowptr = (int*)alloc((size_t)(N + 1) * 4);
    float* dinv   = (float*)alloc((size_t)N * 4);
    int*   bcur   = (int*)alloc((size_t)nb * 4);
    int*   col    = (int*)alloc((size_t)E * 4);
    unsigned int* tmp = (unsigned int*)alloc((size_t)nb * BCAP * 4);  // packed (src<<8)|(dst&255)
    unsigned int*   zsb = (unsigned int*)alloc((size_t)N * 64 * 2);   // bf16 zs = dinv*z (packed)
    unsigned short* hsb = (unsigned short*)alloc((size_t)N * 128 * 2);// bf16 hs = dinv*h
    unsigned short* w1f = (unsigned short*)alloc(8192 * 2);           // W1 frag-major bf16
    unsigned short* w2f = (unsigned short*)alloc(16384 * 2);          // W2 frag-major bf16

    int ntiles = (N + 15) / 16;  // 3125 for N=50000

    // 5 dispatches total
    prep_kernel<<<64, 256, 0, stream>>>(W1, W2, w1f, w2f, bcur, nb);
    partA_kernel<<<(E + 4095) / 4096, 1024, 0, stream>>>(srcp, dstp, bcur, tmp, E);
    bucket_build_kernel<<<nb, 256, 0, stream>>>(tmp, bcur, z, rowptr, dinv, col, zsb, N, nb, E);
    fused1_kernel<<<ntiles, 256, 0, stream>>>((const uint2*)zsb, rowptr, col, dinv, w1f, b1, hsb, N);
    fused2_kernel<<<ntiles, 256, 0, stream>>>((const uint4*)hsb, rowptr, col, dinv,
                                              w2f, b2, out, N);
}

// Round 20
// 113.354 us; speedup vs baseline: 1.2138x; 1.2138x over previous
//
#include <hip/hip_runtime.h>
#include <math.h>

using short8v = __attribute__((ext_vector_type(8))) short;
using f32x4   = __attribute__((ext_vector_type(4))) float;

constexpr int BCAP = 8192;  // per-bucket capacity (mean ~4081, >60 sigma headroom)

// ---------------- bf16 helpers ----------------

__device__ inline float bf_lo(unsigned int p) { return __uint_as_float(p << 16); }
__device__ inline float bf_hi(unsigned int p) { return __uint_as_float(p & 0xffff0000u); }
__device__ inline unsigned short f2bf(float f) {  // round-to-nearest-even
    unsigned int u = __float_as_uint(f);
    u += 0x7fffu + ((u >> 16) & 1u);
    return (unsigned short)(u >> 16);
}
__device__ inline unsigned int pack2bf(float a, float b) {
    return (unsigned int)f2bf(a) | ((unsigned int)f2bf(b) << 16);
}

// ------- prep: init bucket cursors + W1/W2 -> frag-major bf16 in global -------
// frag layout (per MFMA 16x16x32 B-operand): elem index e = ((c*KK+kk)*64 + l)*8 + j
// maps to W[kk*32 + (l>>4)*8 + j][c*16 + (l&15)].

__global__ __launch_bounds__(256)
void prep_kernel(const float* __restrict__ W1, const float* __restrict__ W2,
                 unsigned short* __restrict__ w1f, unsigned short* __restrict__ w2f,
                 int* __restrict__ bcur, int nb) {
    int i = blockIdx.x * 256 + threadIdx.x;
    if (i < nb) bcur[i] = i * BCAP;
    if (i < 8 * 2 * 64 * 8) {  // 8192 = K64 frags (KK=2)
        int j = i & 7, l = (i >> 3) & 63, rest = i >> 9;
        int kk = rest & 1, c = rest >> 1;
        int rk = kk * 32 + (l >> 4) * 8 + j;
        int cc = c * 16 + (l & 15);
        w1f[i] = f2bf(W1[rk * 128 + cc]);
    }
    if (i < 8 * 4 * 64 * 8) {  // 16384 = K128 frags (KK=4)
        int j = i & 7, l = (i >> 3) & 63, rest = i >> 9;
        int kk = rest & 3, c = rest >> 2;
        int rk = kk * 32 + (l >> 4) * 8 + j;
        int cc = c * 16 + (l & 15);
        w2f[i] = f2bf(W2[rk * 128 + cc]);
    }
}

// ---------------- partition: bucket edges by dst>>8; 4096 edges/block ----------------
// packed entry: (src << 8) | (dst & 255)   [valid: N < 65536]

__global__ __launch_bounds__(1024)
void partA_kernel(const int* __restrict__ src, const int* __restrict__ dst,
                  int* __restrict__ bcur, unsigned int* __restrict__ tmp, int E) {
    __shared__ int hist[256];
    __shared__ int chunk[256];
    int t = threadIdx.x;
    if (t < 256) hist[t] = 0;
    __syncthreads();
    int base = blockIdx.x * 4096;
    int s[4], d[4], bb[4], lr[4];
    bool val[4];
#pragma unroll
    for (int k = 0; k < 4; ++k) {
        int i = base + k * 1024 + t;
        val[k] = i < E;
        if (val[k]) {
            s[k] = src[i];
            d[k] = dst[i];
            bb[k] = d[k] >> 8;
            lr[k] = atomicAdd(&hist[bb[k]], 1);  // LDS: local rank in (block,bucket)
        }
    }
    __syncthreads();
    if (t < 256) {
        int c = hist[t];
        chunk[t] = (c > 0) ? atomicAdd(&bcur[t], c) : 0;
    }
    __syncthreads();
#pragma unroll
    for (int k = 0; k < 4; ++k) {
        if (val[k]) tmp[chunk[bb[k]] + lr[k]] = ((unsigned int)s[k] << 8) | (unsigned int)(d[k] & 255);
    }
}

// ------- bucket_build: folded bucket-scan + per-bucket CSR + dinv + prescaled z -------

__global__ __launch_bounds__(256)
void bucket_build_kernel(const unsigned int* __restrict__ tmp, const int* __restrict__ bcur,
                         const float* __restrict__ z, int* __restrict__ rowptr,
                         float* __restrict__ dinv, int* __restrict__ col,
                         unsigned int* __restrict__ zsb, int N, int nb, int E) {
    __shared__ int s[256];
    __shared__ int h[256];
    __shared__ int sc[256];
    __shared__ int cur[256];
    __shared__ float sdv[256];
    __shared__ int s_eb;
    int b = blockIdx.x;
    int t = threadIdx.x;
    // folded bscan: every block scans all bucket counts (196 ints, trivial)
    int cnt_t = (t < nb) ? (bcur[t] - t * BCAP) : 0;
    s[t] = cnt_t;
    __syncthreads();
    for (int off = 1; off < 256; off <<= 1) {
        int u = (t >= off) ? s[t - off] : 0;
        __syncthreads();
        s[t] += u;
        __syncthreads();
    }
    if (t == b) s_eb = s[t] - cnt_t;  // exclusive prefix for this bucket
    if (b == 0 && t == 0) rowptr[N] = E;
    h[t] = 0;
    __syncthreads();
    int eb = s_eb;
    int base = b * BCAP;
    int ecnt = bcur[b] - base;
    // per-node histogram
    for (int i = t; i < ecnt; i += 256) {
        atomicAdd(&h[tmp[base + i] & 255], 1);
    }
    __syncthreads();
    int v = h[t];
    sc[t] = v;
    __syncthreads();
    for (int off = 1; off < 256; off <<= 1) {
        int u = (t >= off) ? sc[t - off] : 0;
        __syncthreads();
        sc[t] += u;
        __syncthreads();
    }
    int excl = sc[t] - v;
    int nd = b * 256 + t;
    float dv = rsqrtf((float)v + 1.0f);  // degree incl. self-loop
    if (nd < N) {
        rowptr[nd] = eb + excl;
        dinv[nd] = dv;
    }
    sdv[t] = dv;
    cur[t] = excl;
    __syncthreads();
    // scatter col (LDS cursors, contiguous window)
    for (int i = t; i < ecnt; i += 256) {
        unsigned int e = tmp[base + i];
        int lpos = atomicAdd(&cur[e & 255], 1);
        col[eb + lpos] = (int)(e >> 8);
    }
    // prescale this block's 256 z-rows: zs = bf16(dinv * z), packed pairs (32 uints/row)
    int nd0 = b * 256;
    for (int idx = t; idx < 256 * 32; idx += 256) {
        int row = idx >> 5;
        int p = idx & 31;
        int node = nd0 + row;
        if (node < N) {
            float2 zv = ((const float2*)z)[(size_t)node * 32 + p];
            float d = sdv[row];
            zsb[(size_t)node * 32 + p] = pack2bf(d * zv.x, d * zv.y);
        }
    }
}

// ------- fused1: [agg64 over zs] -> LDS A-tile -> MFMA W1 -> hs = bf16(dinv.*relu(.+b1)) -------
// 1 tile/block. Phase A: quarter-wave per row (16 lanes x uint2 = 128 B row), SINGLE stream,
// 8-edge unroll = 8 gathers in flight/quarter (round-18 structure — dual-8 gating regressed).
// Phase B: 16x32 col slice per wave.
// mfma_f32_16x16x32_bf16 frags: A lane l: row=l&15, k=(l>>4)*8+j ; B: col=l&15, k=(l>>4)*8+j ;
// C/D: col=l&15, row=(l>>4)*4+j  [m89-verified].

__global__ __launch_bounds__(256)
void fused1_kernel(const uint2* __restrict__ zs4, const int* __restrict__ rowptr,
                   const int* __restrict__ col, const float* __restrict__ dinv,
                   const unsigned short* __restrict__ w1f, const float* __restrict__ b1,
                   unsigned short* __restrict__ hsb, int n) {
    __shared__ unsigned int Atile[16][36];  // row-stride 36 uints (16B pad -> 2-way banks)
    int t = threadIdx.x;
    int wv = t >> 6, lane = t & 63;
    int tile = blockIdx.x;
    int quarter = lane >> 4, ql = lane & 15;  // lane ql holds feats 4ql..4ql+3

    // Phase A: one row per quarter-wave (4 rows in flight per wave)
    {
        int r = wv * 4 + quarter;
        int row = tile * 16 + r;
        float a0 = 0.0f, a1 = 0.0f, a2 = 0.0f, a3 = 0.0f;
        if (row < n) {
            int beg = rowptr[row];
            int end = rowptr[row + 1];
            float di = dinv[row];
            uint2 sp = zs4[(size_t)row * 16 + ql];
            a0 = bf_lo(sp.x); a1 = bf_hi(sp.x);
            a2 = bf_lo(sp.y); a3 = bf_hi(sp.y);
            int e = beg;
            for (; e + 7 < end; e += 8) {
                int c0 = col[e], c1 = col[e + 1], c2 = col[e + 2], c3 = col[e + 3];
                int c4 = col[e + 4], c5 = col[e + 5], c6 = col[e + 6], c7 = col[e + 7];
                uint2 p0 = zs4[(size_t)c0 * 16 + ql];
                uint2 p1 = zs4[(size_t)c1 * 16 + ql];
                uint2 p2 = zs4[(size_t)c2 * 16 + ql];
                uint2 p3 = zs4[(size_t)c3 * 16 + ql];
                uint2 p4 = zs4[(size_t)c4 * 16 + ql];
                uint2 p5 = zs4[(size_t)c5 * 16 + ql];
                uint2 p6 = zs4[(size_t)c6 * 16 + ql];
                uint2 p7 = zs4[(size_t)c7 * 16 + ql];
                a0 += bf_lo(p0.x); a1 += bf_hi(p0.x); a2 += bf_lo(p0.y); a3 += bf_hi(p0.y);
                a0 += bf_lo(p1.x); a1 += bf_hi(p1.x); a2 += bf_lo(p1.y); a3 += bf_hi(p1.y);
                a0 += bf_lo(p2.x); a1 += bf_hi(p2.x); a2 += bf_lo(p2.y); a3 += bf_hi(p2.y);
                a0 += bf_lo(p3.x); a1 += bf_hi(p3.x); a2 += bf_lo(p3.y); a3 += bf_hi(p3.y);
                a0 += bf_lo(p4.x); a1 += bf_hi(p4.x); a2 += bf_lo(p4.y); a3 += bf_hi(p4.y);
                a0 += bf_lo(p5.x); a1 += bf_hi(p5.x); a2 += bf_lo(p5.y); a3 += bf_hi(p5.y);
                a0 += bf_lo(p6.x); a1 += bf_hi(p6.x); a2 += bf_lo(p6.y); a3 += bf_hi(p6.y);
                a0 += bf_lo(p7.x); a1 += bf_hi(p7.x); a2 += bf_lo(p7.y); a3 += bf_hi(p7.y);
            }
            for (; e < end; ++e) {
                uint2 p = zs4[(size_t)col[e] * 16 + ql];
                a0 += bf_lo(p.x); a1 += bf_hi(p.x);
                a2 += bf_lo(p.y); a3 += bf_hi(p.y);
            }
            a0 *= di; a1 *= di; a2 *= di; a3 *= di;
        }
        Atile[r][2 * ql]     = pack2bf(a0, a1);
        Atile[r][2 * ql + 1] = pack2bf(a2, a3);
    }
    __syncthreads();

    // Phase B: wave wv computes cols [wv*32, wv*32+32) = c-frags {wv*2, wv*2+1}
    const short8v* bfr = (const short8v*)w1f;
    const unsigned int* ap = &Atile[0][0];
    short8v af[2];
#pragma unroll
    for (int kk = 0; kk < 2; ++kk) {
        af[kk] = *(const short8v*)(ap + (lane & 15) * 36 + kk * 16 + (lane >> 4) * 4);
    }
    f32x4 acc[2];
#pragma unroll
    for (int ci = 0; ci < 2; ++ci) acc[ci] = (f32x4){0.0f, 0.0f, 0.0f, 0.0f};
#pragma unroll
    for (int kk = 0; kk < 2; ++kk) {
#pragma unroll
        for (int ci = 0; ci < 2; ++ci) {
            int c = wv * 2 + ci;
            acc[ci] = __builtin_amdgcn_mfma_f32_16x16x32_bf16(af[kk], bfr[(c * 2 + kk) * 64 + lane],
                                                              acc[ci], 0, 0, 0);
        }
    }
    int colbase = lane & 15;
    int rowg = (lane >> 4) * 4;
    float dvj[4];
#pragma unroll
    for (int j = 0; j < 4; ++j) {
        int row = tile * 16 + rowg + j;
        dvj[j] = (row < n) ? dinv[row] : 1.0f;
    }
#pragma unroll
    for (int ci = 0; ci < 2; ++ci) {
        int c = wv * 2 + ci;
        float bv = b1[c * 16 + colbase];
#pragma unroll
        for (int j = 0; j < 4; ++j) {
            int row = tile * 16 + rowg + j;
            if (row < n) {
                float v = fmaxf(acc[ci][j] + bv, 0.0f) * dvj[j];
                hsb[(size_t)row * 128 + c * 16 + colbase] = f2bf(v);
            }
        }
    }
}

// ------- fused2: [agg128 over hs] -> LDS A-tile -> MFMA W2 -> out fp32 (+b2) -------
// Phase A: quarter-wave per row (16 lanes x uint4 = 256 B row), DUAL EDGE STREAMS x 4-edge
// unroll = 8 uint4 in flight/quarter; gate is lenB>=4 (deg>=8, ~99.9% of rows — the round-19
// fused1 regression was an 8-gate requiring deg>=16). Lane ql holds feats 8ql..8ql+7.

__global__ __launch_bounds__(256)
void fused2_kernel(const uint4* __restrict__ hs8, const int* __restrict__ rowptr,
                   const int* __restrict__ col, const float* __restrict__ dinv,
                   const unsigned short* __restrict__ w2f, const float* __restrict__ b2,
                   float* __restrict__ out, int n) {
    __shared__ unsigned int Atile[16][68];  // row-stride 68 uints (16B pad)
    int t = threadIdx.x;
    int wv = t >> 6, lane = t & 63;
    int tile = blockIdx.x;
    int quarter = lane >> 4, ql = lane & 15;

    // Phase A: one row per quarter-wave, dual edge streams
    {
        int r = wv * 4 + quarter;
        int row = tile * 16 + r;
        float a0 = 0.0f, a1 = 0.0f, a2 = 0.0f, a3 = 0.0f;
        float a4 = 0.0f, a5 = 0.0f, a6 = 0.0f, a7 = 0.0f;
        float g0 = 0.0f, g1 = 0.0f, g2 = 0.0f, g3 = 0.0f;
        float g4 = 0.0f, g5 = 0.0f, g6 = 0.0f, g7 = 0.0f;
        if (row < n) {
            int beg = rowptr[row];
            int end = rowptr[row + 1];
            float di = dinv[row];
            int mid = beg + ((end - beg + 1) >> 1);  // lenA >= lenB
            uint4 sp = hs8[(size_t)row * 16 + ql];
            a0 = bf_lo(sp.x); a1 = bf_hi(sp.x);
            a2 = bf_lo(sp.y); a3 = bf_hi(sp.y);
            a4 = bf_lo(sp.z); a5 = bf_hi(sp.z);
            a6 = bf_lo(sp.w); a7 = bf_hi(sp.w);
            int e1 = beg, e2 = mid;
            for (; e2 + 3 < end; e1 += 4, e2 += 4) {
                int cA0 = col[e1], cA1 = col[e1 + 1], cA2 = col[e1 + 2], cA3 = col[e1 + 3];
                int cB0 = col[e2], cB1 = col[e2 + 1], cB2 = col[e2 + 2], cB3 = col[e2 + 3];
                uint4 pA0 = hs8[(size_t)cA0 * 16 + ql];
                uint4 pA1 = hs8[(size_t)cA1 * 16 + ql];
                uint4 pA2 = hs8[(size_t)cA2 * 16 + ql];
                uint4 pA3 = hs8[(size_t)cA3 * 16 + ql];
                uint4 pB0 = hs8[(size_t)cB0 * 16 + ql];
                uint4 pB1 = hs8[(size_t)cB1 * 16 + ql];
                uint4 pB2 = hs8[(size_t)cB2 * 16 + ql];
                uint4 pB3 = hs8[(size_t)cB3 * 16 + ql];
                a0 += bf_lo(pA0.x); a1 += bf_hi(pA0.x); a2 += bf_lo(pA0.y); a3 += bf_hi(pA0.y);
                a4 += bf_lo(pA0.z); a5 += bf_hi(pA0.z); a6 += bf_lo(pA0.w); a7 += bf_hi(pA0.w);
                a0 += bf_lo(pA1.x); a1 += bf_hi(pA1.x); a2 += bf_lo(pA1.y); a3 += bf_hi(pA1.y);
                a4 += bf_lo(pA1.z); a5 += bf_hi(pA1.z); a6 += bf_lo(pA1.w); a7 += bf_hi(pA1.w);
                a0 += bf_lo(pA2.x); a1 += bf_hi(pA2.x); a2 += bf_lo(pA2.y); a3 += bf_hi(pA2.y);
                a4 += bf_lo(pA2.z); a5 += bf_hi(pA2.z); a6 += bf_lo(pA2.w); a7 += bf_hi(pA2.w);
                a0 += bf_lo(pA3.x); a1 += bf_hi(pA3.x); a2 += bf_lo(pA3.y); a3 += bf_hi(pA3.y);
                a4 += bf_lo(pA3.z); a5 += bf_hi(pA3.z); a6 += bf_lo(pA3.w); a7 += bf_hi(pA3.w);
                g0 += bf_lo(pB0.x); g1 += bf_hi(pB0.x); g2 += bf_lo(pB0.y); g3 += bf_hi(pB0.y);
                g4 += bf_lo(pB0.z); g5 += bf_hi(pB0.z); g6 += bf_lo(pB0.w); g7 += bf_hi(pB0.w);
                g0 += bf_lo(pB1.x); g1 += bf_hi(pB1.x); g2 += bf_lo(pB1.y); g3 += bf_hi(pB1.y);
                g4 += bf_lo(pB1.z); g5 += bf_hi(pB1.z); g6 += bf_lo(pB1.w); g7 += bf_hi(pB1.w);
                g0 += bf_lo(pB2.x); g1 += bf_hi(pB2.x); g2 += bf_lo(pB2.y); g3 += bf_hi(pB2.y);
                g4 += bf_lo(pB2.z); g5 += bf_hi(pB2.z); g6 += bf_lo(pB2.w); g7 += bf_hi(pB2.w);
                g0 += bf_lo(pB3.x); g1 += bf_hi(pB3.x); g2 += bf_lo(pB3.y); g3 += bf_hi(pB3.y);
                g4 += bf_lo(pB3.z); g5 += bf_hi(pB3.z); g6 += bf_lo(pB3.w); g7 += bf_hi(pB3.w);
            }
            for (; e1 < mid; ++e1) {
                uint4 p = hs8[(size_t)col[e1] * 16 + ql];
                a0 += bf_lo(p.x); a1 += bf_hi(p.x); a2 += bf_lo(p.y); a3 += bf_hi(p.y);
                a4 += bf_lo(p.z); a5 += bf_hi(p.z); a6 += bf_lo(p.w); a7 += bf_hi(p.w);
            }
            for (; e2 < end; ++e2) {
                uint4 p = hs8[(size_t)col[e2] * 16 + ql];
                g0 += bf_lo(p.x); g1 += bf_hi(p.x); g2 += bf_lo(p.y); g3 += bf_hi(p.y);
                g4 += bf_lo(p.z); g5 += bf_hi(p.z); g6 += bf_lo(p.w); g7 += bf_hi(p.w);
            }
            a0 = (a0 + g0) * di; a1 = (a1 + g1) * di;
            a2 = (a2 + g2) * di; a3 = (a3 + g3) * di;
            a4 = (a4 + g4) * di; a5 = (a5 + g5) * di;
            a6 = (a6 + g6) * di; a7 = (a7 + g7) * di;
        }
        Atile[r][4 * ql]     = pack2bf(a0, a1);
        Atile[r][4 * ql + 1] = pack2bf(a2, a3);
        Atile[r][4 * ql + 2] = pack2bf(a4, a5);
        Atile[r][4 * ql + 3] = pack2bf(a6, a7);
    }
    __syncthreads();

    // Phase B: wave wv computes cols [wv*32, wv*32+32) = c-frags {wv*2, wv*2+1}
    const short8v* bfr = (const short8v*)w2f;
    const unsigned int* ap = &Atile[0][0];
    short8v af[4];
#pragma unroll
    for (int kk = 0; kk < 4; ++kk) {
        af[kk] = *(const short8v*)(ap + (lane & 15) * 68 + kk * 16 + (lane >> 4) * 4);
    }
    f32x4 acc[2];
#pragma unroll
    for (int ci = 0; ci < 2; ++ci) acc[ci] = (f32x4){0.0f, 0.0f, 0.0f, 0.0f};
#pragma unroll
    for (int kk = 0; kk < 4; ++kk) {
#pragma unroll
        for (int ci = 0; ci < 2; ++ci) {
            int c = wv * 2 + ci;
            acc[ci] = __builtin_amdgcn_mfma_f32_16x16x32_bf16(af[kk], bfr[(c * 4 + kk) * 64 + lane],
                                                              acc[ci], 0, 0, 0);
        }
    }
    int colbase = lane & 15;
    int rowg = (lane >> 4) * 4;
#pragma unroll
    for (int ci = 0; ci < 2; ++ci) {
        int c = wv * 2 + ci;
        float bv = b2[c * 16 + colbase];
#pragma unroll
        for (int j = 0; j < 4; ++j) {
            int row = tile * 16 + rowg + j;
            if (row < n) {
                out[(size_t)row * 128 + c * 16 + colbase] = acc[ci][j] + bv;
            }
        }
    }
}

// ---------------- launch ----------------

extern "C" void kernel_launch(void* const* d_in, const int* in_sizes, int n_in,
                              void* d_out, int out_size, void* d_ws, size_t ws_size,
                              hipStream_t stream) {
    const float* z  = (const float*)d_in[0];
    const int*   ei = (const int*)d_in[1];
    const float* W1 = (const float*)d_in[2];
    const float* b1 = (const float*)d_in[3];
    const float* W2 = (const float*)d_in[4];
    const float* b2 = (const float*)d_in[5];
    float* out = (float*)d_out;

    int N = in_sizes[0] / 64;
    int E = in_sizes[1] / 2;
    const int* srcp = ei;
    const int* dstp = ei + E;

    char* w = (char*)d_ws;
    auto alloc = [&](size_t bytes) -> char* {
        char* p = w;
        w += (bytes + 255) & ~(size_t)255;
        return p;
    };
    int nb = (N + 255) / 256;  // 196 for N=50000 (must be <= 256)

    int*   rowptr = (int*)alloc((size_t)(N + 1) * 4);
    float* dinv   = (float*)alloc((size_t)N * 4);
    int*   bcur   = (int*)alloc((size_t)nb * 4);
    int*   col    = (int*)alloc((size_t)E * 4);
    unsigned int* tmp = (unsigned int*)alloc((size_t)nb * BCAP * 4);  // packed (src<<8)|(dst&255)
    unsigned int*   zsb = (unsigned int*)alloc((size_t)N * 64 * 2);   // bf16 zs = dinv*z (packed)
    unsigned short* hsb = (unsigned short*)alloc((size_t)N * 128 * 2);// bf16 hs = dinv*h
    unsigned short* w1f = (unsigned short*)alloc(8192 * 2);           // W1 frag-major bf16
    unsigned short* w2f = (unsigned short*)alloc(16384 * 2);          // W2 frag-major bf16

    int ntiles = (N + 15) / 16;  // 3125 for N=50000

    // 5 dispatches total
    prep_kernel<<<64, 256, 0, stream>>>(W1, W2, w1f, w2f, bcur, nb);
    partA_kernel<<<(E + 4095) / 4096, 1024, 0, stream>>>(srcp, dstp, bcur, tmp, E);
    bucket_build_kernel<<<nb, 256, 0, stream>>>(tmp, bcur, z, rowptr, dinv, col, zsb, N, nb, E);
    fused1_kernel<<<ntiles, 256, 0, stream>>>((const uint2*)zsb, rowptr, col, dinv, w1f, b1, hsb, N);
    fused2_kernel<<<ntiles, 256, 0, stream>>>((const uint4*)hsb, rowptr, col, dinv,
                                              w2f, b2, out, N);
}

// Round 21
// 104.975 us; speedup vs baseline: 1.3107x; 1.0798x over previous
//
#include <hip/hip_runtime.h>
#include <math.h>

using short8v = __attribute__((ext_vector_type(8))) short;
using f32x4   = __attribute__((ext_vector_type(4))) float;

constexpr int BCAP = 8192;  // per-bucket capacity (mean ~4081, >60 sigma headroom)

// ---------------- bf16 helpers ----------------

__device__ inline float bf_lo(unsigned int p) { return __uint_as_float(p << 16); }
__device__ inline float bf_hi(unsigned int p) { return __uint_as_float(p & 0xffff0000u); }
__device__ inline unsigned short f2bf(float f) {  // round-to-nearest-even
    unsigned int u = __float_as_uint(f);
    u += 0x7fffu + ((u >> 16) & 1u);
    return (unsigned short)(u >> 16);
}
__device__ inline unsigned int pack2bf(float a, float b) {
    return (unsigned int)f2bf(a) | ((unsigned int)f2bf(b) << 16);
}

// ------- prep: init bucket cursors + W1/W2 -> frag-major bf16 in global -------
// frag layout (per MFMA 16x16x32 B-operand): elem index e = ((c*KK+kk)*64 + l)*8 + j
// maps to W[kk*32 + (l>>4)*8 + j][c*16 + (l&15)].

__global__ __launch_bounds__(256)
void prep_kernel(const float* __restrict__ W1, const float* __restrict__ W2,
                 unsigned short* __restrict__ w1f, unsigned short* __restrict__ w2f,
                 int* __restrict__ bcur, int nb) {
    int i = blockIdx.x * 256 + threadIdx.x;
    if (i < nb) bcur[i] = i * BCAP;
    if (i < 8 * 2 * 64 * 8) {  // 8192 = K64 frags (KK=2)
        int j = i & 7, l = (i >> 3) & 63, rest = i >> 9;
        int kk = rest & 1, c = rest >> 1;
        int rk = kk * 32 + (l >> 4) * 8 + j;
        int cc = c * 16 + (l & 15);
        w1f[i] = f2bf(W1[rk * 128 + cc]);
    }
    if (i < 8 * 4 * 64 * 8) {  // 16384 = K128 frags (KK=4)
        int j = i & 7, l = (i >> 3) & 63, rest = i >> 9;
        int kk = rest & 3, c = rest >> 2;
        int rk = kk * 32 + (l >> 4) * 8 + j;
        int cc = c * 16 + (l & 15);
        w2f[i] = f2bf(W2[rk * 128 + cc]);
    }
}

// ---------------- partition: bucket edges by dst>>8; 4096 edges/block ----------------
// packed entry: (src << 8) | (dst & 255)   [valid: N < 65536]

__global__ __launch_bounds__(1024)
void partA_kernel(const int* __restrict__ src, const int* __restrict__ dst,
                  int* __restrict__ bcur, unsigned int* __restrict__ tmp, int E) {
    __shared__ int hist[256];
    __shared__ int chunk[256];
    int t = threadIdx.x;
    if (t < 256) hist[t] = 0;
    __syncthreads();
    int base = blockIdx.x * 4096;
    int s[4], d[4], bb[4], lr[4];
    bool val[4];
#pragma unroll
    for (int k = 0; k < 4; ++k) {
        int i = base + k * 1024 + t;
        val[k] = i < E;
        if (val[k]) {
            s[k] = src[i];
            d[k] = dst[i];
            bb[k] = d[k] >> 8;
            lr[k] = atomicAdd(&hist[bb[k]], 1);  // LDS: local rank in (block,bucket)
        }
    }
    __syncthreads();
    if (t < 256) {
        int c = hist[t];
        chunk[t] = (c > 0) ? atomicAdd(&bcur[t], c) : 0;
    }
    __syncthreads();
#pragma unroll
    for (int k = 0; k < 4; ++k) {
        if (val[k]) tmp[chunk[bb[k]] + lr[k]] = ((unsigned int)s[k] << 8) | (unsigned int)(d[k] & 255);
    }
}

// ------- bucket_build: folded bucket-scan + per-bucket CSR + dinv + prescaled z -------

__global__ __launch_bounds__(256)
void bucket_build_kernel(const unsigned int* __restrict__ tmp, const int* __restrict__ bcur,
                         const float* __restrict__ z, int* __restrict__ rowptr,
                         float* __restrict__ dinv, int* __restrict__ col,
                         unsigned int* __restrict__ zsb, int N, int nb, int E) {
    __shared__ int s[256];
    __shared__ int h[256];
    __shared__ int sc[256];
    __shared__ int cur[256];
    __shared__ float sdv[256];
    __shared__ int s_eb;
    int b = blockIdx.x;
    int t = threadIdx.x;
    // folded bscan: every block scans all bucket counts (196 ints, trivial)
    int cnt_t = (t < nb) ? (bcur[t] - t * BCAP) : 0;
    s[t] = cnt_t;
    __syncthreads();
    for (int off = 1; off < 256; off <<= 1) {
        int u = (t >= off) ? s[t - off] : 0;
        __syncthreads();
        s[t] += u;
        __syncthreads();
    }
    if (t == b) s_eb = s[t] - cnt_t;  // exclusive prefix for this bucket
    if (b == 0 && t == 0) rowptr[N] = E;
    h[t] = 0;
    __syncthreads();
    int eb = s_eb;
    int base = b * BCAP;
    int ecnt = bcur[b] - base;
    // per-node histogram
    for (int i = t; i < ecnt; i += 256) {
        atomicAdd(&h[tmp[base + i] & 255], 1);
    }
    __syncthreads();
    int v = h[t];
    sc[t] = v;
    __syncthreads();
    for (int off = 1; off < 256; off <<= 1) {
        int u = (t >= off) ? sc[t - off] : 0;
        __syncthreads();
        sc[t] += u;
        __syncthreads();
    }
    int excl = sc[t] - v;
    int nd = b * 256 + t;
    float dv = rsqrtf((float)v + 1.0f);  // degree incl. self-loop
    if (nd < N) {
        rowptr[nd] = eb + excl;
        dinv[nd] = dv;
    }
    sdv[t] = dv;
    cur[t] = excl;
    __syncthreads();
    // scatter col (LDS cursors, contiguous window)
    for (int i = t; i < ecnt; i += 256) {
        unsigned int e = tmp[base + i];
        int lpos = atomicAdd(&cur[e & 255], 1);
        col[eb + lpos] = (int)(e >> 8);
    }
    // prescale this block's 256 z-rows: zs = bf16(dinv * z), packed pairs (32 uints/row)
    int nd0 = b * 256;
    for (int idx = t; idx < 256 * 32; idx += 256) {
        int row = idx >> 5;
        int p = idx & 31;
        int node = nd0 + row;
        if (node < N) {
            float2 zv = ((const float2*)z)[(size_t)node * 32 + p];
            float d = sdv[row];
            zsb[(size_t)node * 32 + p] = pack2bf(d * zv.x, d * zv.y);
        }
    }
}

// ------- fused1: [agg64 over zs] -> LDS A-tile -> MFMA W1 -> hs = bf16(dinv.*relu(.+b1)) -------
// 1 tile/block. Phase A: quarter-wave per row (16 lanes x uint2 = 128 B row), single stream,
// 8-edge unroll = 8 gathers in flight/quarter. Phase B: 16x32 col slice per wave.
// mfma_f32_16x16x32_bf16 frags: A lane l: row=l&15, k=(l>>4)*8+j ; B: col=l&15, k=(l>>4)*8+j ;
// C/D: col=l&15, row=(l>>4)*4+j  [m89-verified].

__global__ __launch_bounds__(256)
void fused1_kernel(const uint2* __restrict__ zs4, const int* __restrict__ rowptr,
                   const int* __restrict__ col, const float* __restrict__ dinv,
                   const unsigned short* __restrict__ w1f, const float* __restrict__ b1,
                   unsigned short* __restrict__ hsb, int n) {
    __shared__ unsigned int Atile[16][36];  // row-stride 36 uints (16B pad -> 2-way banks)
    int t = threadIdx.x;
    int wv = t >> 6, lane = t & 63;
    int tile = blockIdx.x;
    int quarter = lane >> 4, ql = lane & 15;  // lane ql holds feats 4ql..4ql+3

    // Phase A: one row per quarter-wave (4 rows in flight per wave)
    {
        int r = wv * 4 + quarter;
        int row = tile * 16 + r;
        float a0 = 0.0f, a1 = 0.0f, a2 = 0.0f, a3 = 0.0f;
        if (row < n) {
            int beg = rowptr[row];
            int end = rowptr[row + 1];
            float di = dinv[row];
            uint2 sp = zs4[(size_t)row * 16 + ql];
            a0 = bf_lo(sp.x); a1 = bf_hi(sp.x);
            a2 = bf_lo(sp.y); a3 = bf_hi(sp.y);
            int e = beg;
            for (; e + 7 < end; e += 8) {
                int c0 = col[e], c1 = col[e + 1], c2 = col[e + 2], c3 = col[e + 3];
                int c4 = col[e + 4], c5 = col[e + 5], c6 = col[e + 6], c7 = col[e + 7];
                uint2 p0 = zs4[(size_t)c0 * 16 + ql];
                uint2 p1 = zs4[(size_t)c1 * 16 + ql];
                uint2 p2 = zs4[(size_t)c2 * 16 + ql];
                uint2 p3 = zs4[(size_t)c3 * 16 + ql];
                uint2 p4 = zs4[(size_t)c4 * 16 + ql];
                uint2 p5 = zs4[(size_t)c5 * 16 + ql];
                uint2 p6 = zs4[(size_t)c6 * 16 + ql];
                uint2 p7 = zs4[(size_t)c7 * 16 + ql];
                a0 += bf_lo(p0.x); a1 += bf_hi(p0.x); a2 += bf_lo(p0.y); a3 += bf_hi(p0.y);
                a0 += bf_lo(p1.x); a1 += bf_hi(p1.x); a2 += bf_lo(p1.y); a3 += bf_hi(p1.y);
                a0 += bf_lo(p2.x); a1 += bf_hi(p2.x); a2 += bf_lo(p2.y); a3 += bf_hi(p2.y);
                a0 += bf_lo(p3.x); a1 += bf_hi(p3.x); a2 += bf_lo(p3.y); a3 += bf_hi(p3.y);
                a0 += bf_lo(p4.x); a1 += bf_hi(p4.x); a2 += bf_lo(p4.y); a3 += bf_hi(p4.y);
                a0 += bf_lo(p5.x); a1 += bf_hi(p5.x); a2 += bf_lo(p5.y); a3 += bf_hi(p5.y);
                a0 += bf_lo(p6.x); a1 += bf_hi(p6.x); a2 += bf_lo(p6.y); a3 += bf_hi(p6.y);
                a0 += bf_lo(p7.x); a1 += bf_hi(p7.x); a2 += bf_lo(p7.y); a3 += bf_hi(p7.y);
            }
            for (; e < end; ++e) {
                uint2 p = zs4[(size_t)col[e] * 16 + ql];
                a0 += bf_lo(p.x); a1 += bf_hi(p.x);
                a2 += bf_lo(p.y); a3 += bf_hi(p.y);
            }
            a0 *= di; a1 *= di; a2 *= di; a3 *= di;
        }
        Atile[r][2 * ql]     = pack2bf(a0, a1);
        Atile[r][2 * ql + 1] = pack2bf(a2, a3);
    }
    __syncthreads();

    // Phase B: wave wv computes cols [wv*32, wv*32+32) = c-frags {wv*2, wv*2+1}
    const short8v* bfr = (const short8v*)w1f;
    const unsigned int* ap = &Atile[0][0];
    short8v af[2];
#pragma unroll
    for (int kk = 0; kk < 2; ++kk) {
        af[kk] = *(const short8v*)(ap + (lane & 15) * 36 + kk * 16 + (lane >> 4) * 4);
    }
    f32x4 acc[2];
#pragma unroll
    for (int ci = 0; ci < 2; ++ci) acc[ci] = (f32x4){0.0f, 0.0f, 0.0f, 0.0f};
#pragma unroll
    for (int kk = 0; kk < 2; ++kk) {
#pragma unroll
        for (int ci = 0; ci < 2; ++ci) {
            int c = wv * 2 + ci;
            acc[ci] = __builtin_amdgcn_mfma_f32_16x16x32_bf16(af[kk], bfr[(c * 2 + kk) * 64 + lane],
                                                              acc[ci], 0, 0, 0);
        }
    }
    int colbase = lane & 15;
    int rowg = (lane >> 4) * 4;
    float dvj[4];
#pragma unroll
    for (int j = 0; j < 4; ++j) {
        int row = tile * 16 + rowg + j;
        dvj[j] = (row < n) ? dinv[row] : 1.0f;
    }
#pragma unroll
    for (int ci = 0; ci < 2; ++ci) {
        int c = wv * 2 + ci;
        float bv = b1[c * 16 + colbase];
#pragma unroll
        for (int j = 0; j < 4; ++j) {
            int row = tile * 16 + rowg + j;
            if (row < n) {
                float v = fmaxf(acc[ci][j] + bv, 0.0f) * dvj[j];
                hsb[(size_t)row * 128 + c * 16 + colbase] = f2bf(v);
            }
        }
    }
}

// ------- fused2: [agg128 over hs] -> LDS A-tile -> MFMA W2 -> out fp32 (+b2) -------
// Phase A: quarter-wave per row (16 lanes x uint4 = 256 B row), single stream, 4-edge
// unroll = 4 uint4 in flight/quarter (round-18 structure — dual-stream cost VGPR/occupancy).
// Lane ql holds feats 8ql..8ql+7.

__global__ __launch_bounds__(256)
void fused2_kernel(const uint4* __restrict__ hs8, const int* __restrict__ rowptr,
                   const int* __restrict__ col, const float* __restrict__ dinv,
                   const unsigned short* __restrict__ w2f, const float* __restrict__ b2,
                   float* __restrict__ out, int n) {
    __shared__ unsigned int Atile[16][68];  // row-stride 68 uints (16B pad)
    int t = threadIdx.x;
    int wv = t >> 6, lane = t & 63;
    int tile = blockIdx.x;
    int quarter = lane >> 4, ql = lane & 15;

    // Phase A: one row per quarter-wave
    {
        int r = wv * 4 + quarter;
        int row = tile * 16 + r;
        float a0 = 0.0f, a1 = 0.0f, a2 = 0.0f, a3 = 0.0f;
        float a4 = 0.0f, a5 = 0.0f, a6 = 0.0f, a7 = 0.0f;
        if (row < n) {
            int beg = rowptr[row];
            int end = rowptr[row + 1];
            float di = dinv[row];
            uint4 sp = hs8[(size_t)row * 16 + ql];
            a0 = bf_lo(sp.x); a1 = bf_hi(sp.x);
            a2 = bf_lo(sp.y); a3 = bf_hi(sp.y);
            a4 = bf_lo(sp.z); a5 = bf_hi(sp.z);
            a6 = bf_lo(sp.w); a7 = bf_hi(sp.w);
            int e = beg;
            for (; e + 3 < end; e += 4) {
                int c0 = col[e], c1 = col[e + 1], c2 = col[e + 2], c3 = col[e + 3];
                uint4 p0 = hs8[(size_t)c0 * 16 + ql];
                uint4 p1 = hs8[(size_t)c1 * 16 + ql];
                uint4 p2 = hs8[(size_t)c2 * 16 + ql];
                uint4 p3 = hs8[(size_t)c3 * 16 + ql];
                a0 += bf_lo(p0.x); a1 += bf_hi(p0.x); a2 += bf_lo(p0.y); a3 += bf_hi(p0.y);
                a4 += bf_lo(p0.z); a5 += bf_hi(p0.z); a6 += bf_lo(p0.w); a7 += bf_hi(p0.w);
                a0 += bf_lo(p1.x); a1 += bf_hi(p1.x); a2 += bf_lo(p1.y); a3 += bf_hi(p1.y);
                a4 += bf_lo(p1.z); a5 += bf_hi(p1.z); a6 += bf_lo(p1.w); a7 += bf_hi(p1.w);
                a0 += bf_lo(p2.x); a1 += bf_hi(p2.x); a2 += bf_lo(p2.y); a3 += bf_hi(p2.y);
                a4 += bf_lo(p2.z); a5 += bf_hi(p2.z); a6 += bf_lo(p2.w); a7 += bf_hi(p2.w);
                a0 += bf_lo(p3.x); a1 += bf_hi(p3.x); a2 += bf_lo(p3.y); a3 += bf_hi(p3.y);
                a4 += bf_lo(p3.z); a5 += bf_hi(p3.z); a6 += bf_lo(p3.w); a7 += bf_hi(p3.w);
            }
            for (; e < end; ++e) {
                uint4 p = hs8[(size_t)col[e] * 16 + ql];
                a0 += bf_lo(p.x); a1 += bf_hi(p.x); a2 += bf_lo(p.y); a3 += bf_hi(p.y);
                a4 += bf_lo(p.z); a5 += bf_hi(p.z); a6 += bf_lo(p.w); a7 += bf_hi(p.w);
            }
            a0 *= di; a1 *= di; a2 *= di; a3 *= di;
            a4 *= di; a5 *= di; a6 *= di; a7 *= di;
        }
        Atile[r][4 * ql]     = pack2bf(a0, a1);
        Atile[r][4 * ql + 1] = pack2bf(a2, a3);
        Atile[r][4 * ql + 2] = pack2bf(a4, a5);
        Atile[r][4 * ql + 3] = pack2bf(a6, a7);
    }
    __syncthreads();

    // Phase B: wave wv computes cols [wv*32, wv*32+32) = c-frags {wv*2, wv*2+1}
    const short8v* bfr = (const short8v*)w2f;
    const unsigned int* ap = &Atile[0][0];
    short8v af[4];
#pragma unroll
    for (int kk = 0; kk < 4; ++kk) {
        af[kk] = *(const short8v*)(ap + (lane & 15) * 68 + kk * 16 + (lane >> 4) * 4);
    }
    f32x4 acc[2];
#pragma unroll
    for (int ci = 0; ci < 2; ++ci) acc[ci] = (f32x4){0.0f, 0.0f, 0.0f, 0.0f};
#pragma unroll
    for (int kk = 0; kk < 4; ++kk) {
#pragma unroll
        for (int ci = 0; ci < 2; ++ci) {
            int c = wv * 2 + ci;
            acc[ci] = __builtin_amdgcn_mfma_f32_16x16x32_bf16(af[kk], bfr[(c * 4 + kk) * 64 + lane],
                                                              acc[ci], 0, 0, 0);
        }
    }
    int colbase = lane & 15;
    int rowg = (lane >> 4) * 4;
#pragma unroll
    for (int ci = 0; ci < 2; ++ci) {
        int c = wv * 2 + ci;
        float bv = b2[c * 16 + colbase];
#pragma unroll
        for (int j = 0; j < 4; ++j) {
            int row = tile * 16 + rowg + j;
            if (row < n) {
                out[(size_t)row * 128 + c * 16 + colbase] = acc[ci][j] + bv;
            }
        }
    }
}

// ---------------- launch ----------------

extern "C" void kernel_launch(void* const* d_in, const int* in_sizes, int n_in,
                              void* d_out, int out_size, void* d_ws, size_t ws_size,
                              hipStream_t stream) {
    const float* z  = (const float*)d_in[0];
    const int*   ei = (const int*)d_in[1];
    const float* W1 = (const float*)d_in[2];
    const float* b1 = (const float*)d_in[3];
    const float* W2 = (const float*)d_in[4];
    const float* b2 = (const float*)d_in[5];
    float* out = (float*)d_out;

    int N = in_sizes[0] / 64;
    int E = in_sizes[1] / 2;
    const int* srcp = ei;
    const int* dstp = ei + E;

    char* w = (char*)d_ws;
    auto alloc = [&](size_t bytes) -> char* {
        char* p = w;
        w += (bytes + 255) & ~(size_t)255;
        return p;
    };
    int nb = (N + 255) / 256;  // 196 for N=50000 (must be <= 256)

    int*   rowptr = (int*)alloc((size_t)(N + 1) * 4);
    float* dinv   = (float*)alloc((size_t)N * 4);
    int*   bcur   = (int*)alloc((size_t)nb * 4);
    int*   col    = (int*)alloc((size_t)E * 4);
    unsigned int* tmp = (unsigned int*)alloc((size_t)nb * BCAP * 4);  // packed (src<<8)|(dst&255)
    unsigned int*   zsb = (unsigned int*)alloc((size_t)N * 64 * 2);   // bf16 zs = dinv*z (packed)
    unsigned short* hsb = (unsigned short*)alloc((size_t)N * 128 * 2);// bf16 hs = dinv*h
    unsigned short* w1f = (unsigned short*)alloc(8192 * 2);           // W1 frag-major bf16
    unsigned short* w2f = (unsigned short*)alloc(16384 * 2);          // W2 frag-major bf16

    int ntiles = (N + 15) / 16;  // 3125 for N=50000

    // 5 dispatches total
    prep_kernel<<<64, 256, 0, stream>>>(W1, W2, w1f, w2f, bcur, nb);
    partA_kernel<<<(E + 4095) / 4096, 1024, 0, stream>>>(srcp, dstp, bcur, tmp, E);
    bucket_build_kernel<<<nb, 256, 0, stream>>>(tmp, bcur, z, rowptr, dinv, col, zsb, N, nb, E);
    fused1_kernel<<<ntiles, 256, 0, stream>>>((const uint2*)zsb, rowptr, col, dinv, w1f, b1, hsb, N);
    fused2_kernel<<<ntiles, 256, 0, stream>>>((const uint4*)hsb, rowptr, col, dinv,
                                              w2f, b2, out, N);
}